// Round 6
// baseline (134745.007 us; speedup 1.0000x reference)
//
#include <hip/hip_runtime.h>

#define SEQ 256

// ws layout (float offsets)
#define WT_FCW 0u         // fc_w^T  [256][2048]
#define WT_MAP 524288u    // map_w^T [2048][512]
#define WT_IH0 1572864u   // wih0^T  [512][2048]
#define WT_HH0 2621440u   // whh0^T  [512][2048]
#define WT_IH1 3670016u   // wih1^T  [512][2048]
#define WT_HH1 4718592u   // whh1^T  [512][2048]
#define OFF_H  5767168u   // [set][layer][p][512] ; set stride 262144, layer stride 131072
#define OFF_C  6291456u
#define OFF_XM 6815744u   // sigmoid(map) f32 [256][512]
#define OFF_X0 6946816u   // raw h2 of layer0 f32 [256][512]
// end: 7077888 floats = 28.3 MB

__device__ __forceinline__ float sigf(float x){ return 1.0f/(1.0f + __expf(-x)); }
__device__ __forceinline__ float tanhf_(float x){
  float cx = fminf(fmaxf(x, -15.f), 15.f);
  float e = __expf(2.f*cx);
  return (e-1.f)/(e+1.f);
}

// ---------- transpose: dst[c][r] = src[r][c], dst stride R ----------
__global__ __launch_bounds__(256) void tr_kernel(const float* __restrict__ src,
                                                 float* __restrict__ dst, int R, int C){
  int i = blockIdx.x*256 + threadIdx.x;
  if (i < R*C){ int r = i / C, c = i - r*C; dst[(size_t)c*R + r] = src[i]; }
}

// ---------- init: dec=tanh(latent@fc_w.T+fc_b); scatter via flat reshape formula ----------
// dec[b][n], flat f=b*2048+n -> (2,256,1024): l=f>>18, p=(f>>10)&255, q=f&1023;
// q<512 -> h[l][p][q], else c[l][p][q-512]
__global__ __launch_bounds__(256) void init2(const float* __restrict__ latent,
                                             const float* __restrict__ fc_b,
                                             float* __restrict__ ws){
  __shared__ float ls[256];
  const int b = blockIdx.x, tid = threadIdx.x;
  ls[tid] = latent[b*256 + tid];
  __syncthreads();
  const float* fT = ws + WT_FCW;           // [k][n] stride 2048
  for (int nc = 0; nc < 8; ++nc){
    const int n = nc*256 + tid;
    float acc = fc_b[n];
    for (int k = 0; k < 256; ++k) acc += ls[k] * fT[k*2048 + n];
    const float v = tanhf_(acc);
    const unsigned f = (unsigned)b*2048u + (unsigned)n;
    const unsigned l = f >> 18, p = (f >> 10) & 255u, q = f & 1023u;
    ws[(q < 512u ? OFF_H : OFF_C) + l*131072u + p*512u + (q & 511u)] = v;
  }
}

// ---------- map + sigmoid + output (f32!) ----------
// fc_in[r][k]: f=r*2048+k -> l=f>>18, p=(f>>10)&255, q=f&1023 -> h/c[l][p][q&511]
__global__ __launch_bounds__(256) void map2(float* __restrict__ ws,
                                            const float* __restrict__ map_b,
                                            float* __restrict__ outp, int cur){
  __shared__ float xs[4][2048];
  const int tid = threadIdx.x, nc = blockIdx.x, r0 = blockIdx.y*4;
  for (int i = tid; i < 4*2048; i += 256){
    const int rr = i >> 11, kk = i & 2047;
    const unsigned f = (unsigned)(r0 + rr)*2048u + (unsigned)kk;
    const unsigned l = f >> 18, p = (f >> 10) & 255u, q = f & 1023u;
    xs[rr][kk] = ws[(q < 512u ? OFF_H : OFF_C) + (unsigned)cur*262144u
                    + l*131072u + p*512u + (q & 511u)];
  }
  __syncthreads();
  const int n = nc*256 + tid;
  const float* mT = ws + WT_MAP;           // [k][n] stride 512
  float a0=0.f, a1=0.f, a2=0.f, a3=0.f;
  for (int k = 0; k < 2048; ++k){
    const float w = mT[k*512 + n];
    a0 += xs[0][k]*w; a1 += xs[1][k]*w; a2 += xs[2][k]*w; a3 += xs[3][k]*w;
  }
  const float bb = map_b[n];
  const float v0 = sigf(a0+bb), v1 = sigf(a1+bb), v2 = sigf(a2+bb), v3 = sigf(a3+bb);
  ws[OFF_XM + (r0+0)*512 + n] = v0;
  ws[OFF_XM + (r0+1)*512 + n] = v1;
  ws[OFF_XM + (r0+2)*512 + n] = v2;
  ws[OFF_XM + (r0+3)*512 + n] = v3;
  outp[(r0+0)*512 + n] = v0;               // f32 output — the round-3/4/5 bug was bf16-packing here
  outp[(r0+1)*512 + n] = v1;
  outp[(r0+2)*512 + n] = v2;
  outp[(r0+3)*512 + n] = v3;
}

// ---------- lstm layer: plain dot products on transposed weights ----------
__global__ __launch_bounds__(256) void lstm2(float* __restrict__ ws,
                                             const float* __restrict__ bih,
                                             const float* __restrict__ bhh,
                                             int layer, int cur){
  __shared__ float xs[4][512];
  __shared__ float hh[4][512];
  const int tid = threadIdx.x, nc = blockIdx.x, r0 = blockIdx.y*4;
  const float* xsrc = ws + (layer == 0 ? OFF_XM : OFF_X0);
  const float* hsrc = ws + OFF_H + (unsigned)cur*262144u + (unsigned)layer*131072u;
  const float* csrc = ws + OFF_C + (unsigned)cur*262144u + (unsigned)layer*131072u;
  const int nxt = cur ^ 1;
  float* hdst = ws + OFF_H + (unsigned)nxt*262144u + (unsigned)layer*131072u;
  float* cdst = ws + OFF_C + (unsigned)nxt*262144u + (unsigned)layer*131072u;
  float* x0   = ws + OFF_X0;

  for (int i = tid; i < 4*512; i += 256){
    const int rr = i >> 9, kk = i & 511;
    xs[rr][kk] = xsrc[(r0+rr)*512 + kk];
    hh[rr][kk] = hsrc[(r0+rr)*512 + kk];
  }
  __syncthreads();
  const int j = nc*256 + tid;
  const float* iT = ws + (layer == 0 ? WT_IH0 : WT_IH1);   // [k][g*512+j] stride 2048
  const float* hT = ws + (layer == 0 ? WT_HH0 : WT_HH1);
  float ai[4]={0,0,0,0}, af[4]={0,0,0,0}, ag[4]={0,0,0,0}, ao[4]={0,0,0,0};
  for (int k = 0; k < 512; ++k){
    const float wi0 = iT[k*2048 + j],        wi1 = iT[k*2048 + 512 + j];
    const float wi2 = iT[k*2048 + 1024 + j], wi3 = iT[k*2048 + 1536 + j];
    const float wh0 = hT[k*2048 + j],        wh1 = hT[k*2048 + 512 + j];
    const float wh2 = hT[k*2048 + 1024 + j], wh3 = hT[k*2048 + 1536 + j];
    #pragma unroll
    for (int rr = 0; rr < 4; ++rr){
      const float xv = xs[rr][k], hv = hh[rr][k];
      ai[rr] += xv*wi0 + hv*wh0;
      af[rr] += xv*wi1 + hv*wh1;
      ag[rr] += xv*wi2 + hv*wh2;
      ao[rr] += xv*wi3 + hv*wh3;
    }
  }
  const float b_i = bih[j]        + bhh[j];
  const float b_f = bih[512 + j]  + bhh[512 + j];
  const float b_g = bih[1024 + j] + bhh[1024 + j];
  const float b_o = bih[1536 + j] + bhh[1536 + j];
  #pragma unroll
  for (int rr = 0; rr < 4; ++rr){
    const int r = r0 + rr;
    const float cp = csrc[r*512 + j];
    const float c2 = sigf(af[rr] + b_f)*cp + sigf(ai[rr] + b_i)*tanhf_(ag[rr] + b_g);
    const float h2 = sigf(ao[rr] + b_o)*tanhf_(c2);
    if (layer == 0) x0[r*512 + j] = h2;    // raw h2 feeds layer 1
    hdst[r*512 + j] = tanhf_(h2);          // carry is tanh-squashed
    cdst[r*512 + j] = tanhf_(c2);
  }
}

extern "C" void kernel_launch(void* const* d_in, const int* in_sizes, int n_in,
                              void* d_out, int out_size, void* d_ws, size_t ws_size,
                              hipStream_t stream)
{
  (void)in_sizes; (void)n_in; (void)out_size; (void)ws_size;
  const float* latent = (const float*)d_in[0];
  const float* fc_w   = (const float*)d_in[1];
  const float* fc_b   = (const float*)d_in[2];
  const float* map_w  = (const float*)d_in[3];
  const float* map_b  = (const float*)d_in[4];
  const float* bih0   = (const float*)d_in[7];
  const float* bhh0   = (const float*)d_in[8];
  const float* bih1   = (const float*)d_in[11];
  const float* bhh1   = (const float*)d_in[12];
  float* ws = (float*)d_ws;
  float* outp = (float*)d_out;

  tr_kernel<<<2048,256,0,stream>>>(fc_w,  ws + WT_FCW, 2048, 256);
  tr_kernel<<<4096,256,0,stream>>>(map_w, ws + WT_MAP, 512, 2048);
  tr_kernel<<<4096,256,0,stream>>>((const float*)d_in[5],  ws + WT_IH0, 2048, 512);
  tr_kernel<<<4096,256,0,stream>>>((const float*)d_in[6],  ws + WT_HH0, 2048, 512);
  tr_kernel<<<4096,256,0,stream>>>((const float*)d_in[9],  ws + WT_IH1, 2048, 512);
  tr_kernel<<<4096,256,0,stream>>>((const float*)d_in[10], ws + WT_HH1, 2048, 512);
  init2<<<256,256,0,stream>>>(latent, fc_b, ws);
  for (int t = 0; t < SEQ; ++t) {
    const int cur = t & 1;
    map2<<<dim3(2,64),256,0,stream>>>(ws, map_b, outp + (size_t)t*131072u, cur);
    lstm2<<<dim3(2,64),256,0,stream>>>(ws, bih0, bhh0, 0, cur);
    lstm2<<<dim3(2,64),256,0,stream>>>(ws, bih1, bhh1, 1, cur);
  }
}

// Round 7
// 60259.283 us; speedup vs baseline: 2.2361x; 2.2361x over previous
//
#include <hip/hip_runtime.h>

#define SEQ 256

// ws layout (float offsets)
#define WL0    0u          // lstm0 fused W' [c=j*4+g][k=1024] (k<512: wih, else whh)
#define WL1    2097152u    // lstm1 fused W'
#define FCT    4194304u    // fc_w^T [k=256][n=2048]
#define OFF_H  4718592u    // [set][layer][p][512]; set stride 262144, layer stride 131072
#define OFF_C  5242880u
#define OFF_XM 5767168u    // sigmoid(map) f32 [256][512]
#define OFF_X0 5898240u    // raw h2 of layer0 f32 [256][512]
#define OFF_MP 6029312u    // map split-K partials [2][256][512]
// end: 6291456 floats = 25.2 MB

__device__ __forceinline__ float sigf(float x){ return 1.0f/(1.0f + __expf(-x)); }
__device__ __forceinline__ float tanhf_(float x){
  float cx = fminf(fmaxf(x, -15.f), 15.f);
  float e = __expf(2.f*cx);
  return (e-1.f)/(e+1.f);
}

// ---------- one-time: transpose fc_w -> FCT[k][n] ----------
__global__ __launch_bounds__(256) void tr_kernel(const float* __restrict__ src,
                                                 float* __restrict__ dst, int R, int C){
  int i = blockIdx.x*256 + threadIdx.x;
  if (i < R*C){ int r = i / C, c = i - r*C; dst[(size_t)c*R + r] = src[i]; }
}

// ---------- one-time: build fused gate-interleaved LSTM weights ----------
// W'[layer][c][k], c=j*4+g: k<512 -> wih[g*512+j][k], else whh[g*512+j][k-512]
__global__ __launch_bounds__(256) void wprep(const float* __restrict__ wih0,
                                             const float* __restrict__ whh0,
                                             const float* __restrict__ wih1,
                                             const float* __restrict__ whh1,
                                             float* __restrict__ ws){
  const unsigned idx = blockIdx.x*256u + threadIdx.x;     // [0, 4194304)
  const unsigned layer = idx >> 21, rem = idx & 2097151u;
  const unsigned c = rem >> 10, k = rem & 1023u;
  const unsigned j = c >> 2, g = c & 3u;
  const float* wih = layer ? wih1 : wih0;
  const float* whh = layer ? whh1 : whh0;
  const float v = (k < 512u) ? wih[(g*512u + j)*512u + k] : whh[(g*512u + j)*512u + (k - 512u)];
  ws[(layer ? WL1 : WL0) + rem] = v;
}

// ---------- init: dec=tanh(latent@fc_w.T+fc_b); scatter via flat reshape formula ----------
__global__ __launch_bounds__(256) void init2(const float* __restrict__ latent,
                                             const float* __restrict__ fc_b,
                                             float* __restrict__ ws){
  __shared__ float ls[256];
  const int b = blockIdx.x, tid = threadIdx.x;
  ls[tid] = latent[b*256 + tid];
  __syncthreads();
  const float* fT = ws + FCT;              // [k][n] stride 2048
  for (int nc = 0; nc < 8; ++nc){
    const int n = nc*256 + tid;
    float acc = fc_b[n];
    for (int k = 0; k < 256; ++k) acc += ls[k] * fT[k*2048 + n];
    const float v = tanhf_(acc);
    const unsigned f = (unsigned)b*2048u + (unsigned)n;
    const unsigned l = f >> 18, p = (f >> 10) & 255u, q = f & 1023u;
    ws[(q < 512u ? OFF_H : OFF_C) + l*131072u + p*512u + (q & 511u)] = v;
  }
}

// ---------- map partial GEMM: BM=128, BN=8, split-K=2, BK=32 ----------
// grid (64 n-blocks, 2 row-blocks, 2 k-parts), 256 thr = 8 cols x 32 rowgroups(4 rows)
__global__ __launch_bounds__(256) void map3(const float* __restrict__ map_w,
                                            float* __restrict__ ws, int cur){
  __shared__ float As[32*132];             // [k][r], stride 132
  const int tid = threadIdx.x;
  const int cb = blockIdx.x, rb = blockIdx.y, kp = blockIdx.z;
  const int c = tid & 7, rg = tid >> 3;
  const int n = cb*8 + c;
  const float* wp = map_w + (size_t)n*2048 + kp*1024;
  float acc[4] = {0.f,0.f,0.f,0.f};

  for (int chunk = 0; chunk < 32; ++chunk){
    const int k0 = chunk*32;               // within this k-part
    // stage A[128 rows][32 k] via concat-reshape gather
    const unsigned base = (k0 < 512 ? OFF_H : OFF_C) + (unsigned)cur*262144u;
    #pragma unroll
    for (int it = 0; it < 4; ++it){
      const int idx = tid + it*256;        // [0,1024)
      const int r = idx >> 3, kq = idx & 7;
      const int rglob = rb*128 + r;
      const unsigned rowbase = base + (unsigned)(rglob >> 7)*131072u
                             + (unsigned)((rglob & 127)*2 + kp)*512u;
      const float4 v = *(const float4*)&ws[rowbase + (unsigned)((k0 & 511) + kq*4)];
      const int kk = kq*4;
      As[(kk+0)*132 + r] = v.x;
      As[(kk+1)*132 + r] = v.y;
      As[(kk+2)*132 + r] = v.z;
      As[(kk+3)*132 + r] = v.w;
    }
    __syncthreads();
    #pragma unroll
    for (int kq = 0; kq < 8; ++kq){
      const float4 w4 = *(const float4*)(wp + k0 + kq*4);
      #pragma unroll
      for (int i = 0; i < 4; ++i){
        const float wv = (i==0)?w4.x:(i==1)?w4.y:(i==2)?w4.z:w4.w;
        const float4 a4 = *(const float4*)&As[(kq*4+i)*132 + rg*4];
        acc[0] += a4.x*wv; acc[1] += a4.y*wv; acc[2] += a4.z*wv; acc[3] += a4.w*wv;
      }
    }
    __syncthreads();
  }
  float* mp = ws + OFF_MP + (unsigned)kp*131072u;
  #pragma unroll
  for (int i = 0; i < 4; ++i)
    mp[(rb*128 + rg*4 + i)*512 + n] = acc[i];
}

// ---------- map finalize: sum 2 partials + bias -> sigmoid -> XM + out ----------
__global__ __launch_bounds__(256) void fin3(const float* __restrict__ map_b,
                                            float* __restrict__ ws,
                                            float* __restrict__ outp){
  const int idx = blockIdx.x*256 + threadIdx.x;   // [0,131072)
  const int nn = idx & 511;
  const float v = sigf(ws[OFF_MP + idx] + ws[OFF_MP + 131072 + idx] + map_b[nn]);
  ws[OFF_XM + idx] = v;
  outp[idx] = v;
}

// ---------- lstm GEMM + cell: BM=128, BN=8 (=2 j x 4 gates), K=1024, BK=32 ----------
// grid (256 c-blocks, 2 row-blocks); 256 thr = 8 cols x 32 rowgroups(4 rows)
__global__ __launch_bounds__(256) void lstm3(float* __restrict__ ws,
                                             const float* __restrict__ bih,
                                             const float* __restrict__ bhh,
                                             int layer, int cur){
  __shared__ float As[32*132];
  const int tid = threadIdx.x;
  const int cb = blockIdx.x, rb = blockIdx.y;
  const int c = tid & 7, rg = tid >> 3;
  const float* W  = ws + (layer ? WL1 : WL0);
  const float* xsrc = ws + (layer == 0 ? OFF_XM : OFF_X0);
  const float* hsrc = ws + OFF_H + (unsigned)cur*262144u + (unsigned)layer*131072u;
  const float* csrc = ws + OFF_C + (unsigned)cur*262144u + (unsigned)layer*131072u;
  const int nxt = cur ^ 1;
  float* hdst = ws + OFF_H + (unsigned)nxt*262144u + (unsigned)layer*131072u;
  float* cdst = ws + OFF_C + (unsigned)nxt*262144u + (unsigned)layer*131072u;
  float* x0   = ws + OFF_X0;

  const float* wp = W + (size_t)(cb*8 + c)*1024;
  float acc[4] = {0.f,0.f,0.f,0.f};

  for (int chunk = 0; chunk < 32; ++chunk){
    const int k0 = chunk*32;               // [0,1024); <512 -> x, else h
    const float* src = (k0 < 512) ? xsrc : hsrc;
    const int koff = k0 & 511;
    #pragma unroll
    for (int it = 0; it < 4; ++it){
      const int idx = tid + it*256;
      const int r = idx >> 3, kq = idx & 7;
      const float4 v = *(const float4*)&src[(rb*128 + r)*512 + koff + kq*4];
      const int kk = kq*4;
      As[(kk+0)*132 + r] = v.x;
      As[(kk+1)*132 + r] = v.y;
      As[(kk+2)*132 + r] = v.z;
      As[(kk+3)*132 + r] = v.w;
    }
    __syncthreads();
    #pragma unroll
    for (int kq = 0; kq < 8; ++kq){
      const float4 w4 = *(const float4*)(wp + k0 + kq*4);
      #pragma unroll
      for (int i = 0; i < 4; ++i){
        const float wv = (i==0)?w4.x:(i==1)?w4.y:(i==2)?w4.z:w4.w;
        const float4 a4 = *(const float4*)&As[(kq*4+i)*132 + rg*4];
        acc[0] += a4.x*wv; acc[1] += a4.y*wv; acc[2] += a4.z*wv; acc[3] += a4.w*wv;
      }
    }
    __syncthreads();
  }
  // gate exchange through LDS: gsum[c][128 rows]
  #pragma unroll
  for (int i = 0; i < 4; ++i) As[c*128 + rg*4 + i] = acc[i];
  __syncthreads();
  // one (row, j) state per thread
  const int r = tid & 127, jj = tid >> 7;
  const int row = rb*128 + r;
  const int j = cb*2 + jj;
  const float gi = As[(jj*4+0)*128 + r] + bih[j]        + bhh[j];
  const float gf = As[(jj*4+1)*128 + r] + bih[512 + j]  + bhh[512 + j];
  const float gg = As[(jj*4+2)*128 + r] + bih[1024 + j] + bhh[1024 + j];
  const float go = As[(jj*4+3)*128 + r] + bih[1536 + j] + bhh[1536 + j];
  const float cp = csrc[row*512 + j];
  const float c2 = sigf(gf)*cp + sigf(gi)*tanhf_(gg);
  const float h2 = sigf(go)*tanhf_(c2);
  if (layer == 0) x0[row*512 + j] = h2;    // raw h2 feeds layer 1
  hdst[row*512 + j] = tanhf_(h2);          // carry is tanh-squashed
  cdst[row*512 + j] = tanhf_(c2);
}

extern "C" void kernel_launch(void* const* d_in, const int* in_sizes, int n_in,
                              void* d_out, int out_size, void* d_ws, size_t ws_size,
                              hipStream_t stream)
{
  (void)in_sizes; (void)n_in; (void)out_size; (void)ws_size;
  const float* latent = (const float*)d_in[0];
  const float* fc_w   = (const float*)d_in[1];
  const float* fc_b   = (const float*)d_in[2];
  const float* map_w  = (const float*)d_in[3];
  const float* map_b  = (const float*)d_in[4];
  const float* wih0   = (const float*)d_in[5];
  const float* whh0   = (const float*)d_in[6];
  const float* bih0   = (const float*)d_in[7];
  const float* bhh0   = (const float*)d_in[8];
  const float* wih1   = (const float*)d_in[9];
  const float* whh1   = (const float*)d_in[10];
  const float* bih1   = (const float*)d_in[11];
  const float* bhh1   = (const float*)d_in[12];
  float* ws = (float*)d_ws;
  float* outp = (float*)d_out;

  tr_kernel<<<2048,256,0,stream>>>(fc_w, ws + FCT, 2048, 256);
  wprep<<<16384,256,0,stream>>>(wih0, whh0, wih1, whh1, ws);
  init2<<<256,256,0,stream>>>(latent, fc_b, ws);
  for (int t = 0; t < SEQ; ++t) {
    const int cur = t & 1;
    map3<<<dim3(64,2,2),256,0,stream>>>(map_w, ws, cur);
    fin3<<<512,256,0,stream>>>(map_b, ws, outp + (size_t)t*131072u);
    lstm3<<<dim3(256,2),256,0,stream>>>(ws, bih0, bhh0, 0, cur);
    lstm3<<<dim3(256,2),256,0,stream>>>(ws, bih1, bhh1, 1, cur);
  }
}